// Round 6
// baseline (235.976 us; speedup 1.0000x reference)
//
#include <hip/hip_runtime.h>
#include <hip/hip_bf16.h>

typedef __bf16 bf16_t;
typedef __bf16 bf16x8 __attribute__((ext_vector_type(8)));
typedef __bf16 bf16x4 __attribute__((ext_vector_type(4)));
typedef float f32x4 __attribute__((ext_vector_type(4)));

#define NB 8
#define NS 4096
#define NH 256
#define NF 512
#define NE 16
#define NTOK (NB*NS)          // 32768
#define TT 64                 // tokens per tile
#define NCH 16                // f-chunks of 32
#define HS_STRIDE 40          // 32 + 8 pad (80B = 5*16: rows 16B-aligned)

// async global->LDS, 16B per lane, linear LDS dest (wave-uniform base + lane*16)
__device__ __forceinline__ void load_lds16(const void* g, void* l) {
    __builtin_amdgcn_global_load_lds(
        (const __attribute__((address_space(1))) unsigned int*)g,
        (__attribute__((address_space(3))) unsigned int*)l, 16, 0, 0);
}

// ---------------------------------------------------------------------------
// Kernel 1 (fused prep): gate blocks [0,128) + transpose blocks [128,4224).
// Gate blocks dispatched first so their long per-token loop overlaps the 4096
// short transpose blocks.
// transpose: w1 [E][H][F] -> w1t [E][F][H] bf16, k-index XOR bank-swizzled:
//   element (f,k) at f*256 + ((k>>3)^(f&7))*8 + (k&7)
// w2 [E][F][H] -> w2t [E][F/32][H][32] bf16 chunked (per-chunk contiguous 16KB)
// gate: fp32 logits, top-2, softmax(2), hierarchical scatter + x->bf16 (xb)
// ---------------------------------------------------------------------------
__global__ __launch_bounds__(256) void prep_kernel(
    const float* __restrict__ w1, const float* __restrict__ w2,
    bf16_t* __restrict__ w1t, bf16_t* __restrict__ w2t,
    const float* __restrict__ x, const float* __restrict__ gate_w,
    const float* __restrict__ gate_b,
    int* __restrict__ counts, int* __restrict__ bucket_enc,
    float* __restrict__ bucket_gw, bf16_t* __restrict__ xb)
{
    __shared__ float tile[32][33];
    __shared__ int lcnt[NE];
    __shared__ int gbase[NE];

    if (blockIdx.x < 128) {
        // ---------------- gate body ----------------
        if (threadIdx.x < NE) lcnt[threadIdx.x] = 0;
        __syncthreads();

        int tok = blockIdx.x * 256 + threadIdx.x;
        const float4* xr = (const float4*)(x + (size_t)tok * NH);
        bf16x4* xbr = (bf16x4*)(xb + (size_t)tok * NH);
        float acc[NE];
        #pragma unroll
        for (int e = 0; e < NE; e++) acc[e] = gate_b[e];
        for (int h4 = 0; h4 < NH / 4; h4++) {
            float4 xv = xr[h4];
            bf16x4 xo;
            xo[0] = (bf16_t)xv.x; xo[1] = (bf16_t)xv.y;
            xo[2] = (bf16_t)xv.z; xo[3] = (bf16_t)xv.w;
            xbr[h4] = xo;
            #pragma unroll
            for (int j = 0; j < 4; j++) {
                float xs = (j == 0) ? xv.x : (j == 1) ? xv.y : (j == 2) ? xv.z : xv.w;
                const float* wr = gate_w + (h4 * 4 + j) * NE;  // uniform -> s_load
                #pragma unroll
                for (int e = 0; e < NE; e++) acc[e] += xs * wr[e];
            }
        }
        // top-2 (jax.lax.top_k order: strict >, earlier index wins ties)
        float v0 = -1e30f, v1 = -1e30f; int i0 = 0, i1 = 0;
        #pragma unroll
        for (int e = 0; e < NE; e++) {
            float a = acc[e];
            if (a > v0)      { v1 = v0; i1 = i0; v0 = a; i0 = e; }
            else if (a > v1) { v1 = a; i1 = e; }
        }
        float e1 = __expf(v1 - v0);
        float s  = 1.f + e1;
        int   pe[2] = { i0, i1 };
        float pg[2] = { 1.f / s, e1 / s };
        int   po[2];
        po[0] = atomicAdd(&lcnt[i0], 1);
        po[1] = atomicAdd(&lcnt[i1], 1);
        __syncthreads();
        if (threadIdx.x < NE)
            gbase[threadIdx.x] = atomicAdd(&counts[threadIdx.x], lcnt[threadIdx.x]);
        __syncthreads();
        #pragma unroll
        for (int k = 0; k < 2; k++) {
            int e = pe[k];
            int pos = gbase[e] + po[k];
            bucket_enc[e * NTOK + pos] = tok | (k << 20);
            bucket_gw [e * NTOK + pos] = pg[k];
        }
        return;
    }

    // ---------------- transpose body ----------------
    int bid = blockIdx.x - 128;
    const float* src; bf16_t* dst; int R, C; int isw1;
    if (bid < 2048) { src = w1; dst = w1t; R = NH; C = NF; isw1 = 1; }
    else            { bid -= 2048; src = w2; dst = w2t; R = NF; C = NH; isw1 = 0; }
    int e = bid >> 7;
    int t = bid & 127;
    int tcols = C / 32;
    int tr = (t / tcols) * 32, tc = (t % tcols) * 32;
    src += (size_t)e * R * C;
    dst += (size_t)e * R * C;
    int tx = threadIdx.x & 31, ty0 = threadIdx.x >> 5;
    #pragma unroll
    for (int i = 0; i < 4; i++) {
        int ty = ty0 + i * 8;
        tile[ty][tx] = src[(size_t)(tr + ty) * C + tc + tx];
    }
    __syncthreads();
    if (threadIdx.x < 128) {
        int j = threadIdx.x & 31;   // output-row local index
        int g = threadIdx.x >> 5;   // which group of 8 output-cols
        bf16x8 v;
        #pragma unroll
        for (int jj = 0; jj < 8; jj++)
            v[jj] = (bf16_t)tile[g * 8 + jj][j];
        size_t idx;
        if (isw1) {
            int f  = tc + j;          // output row
            int kb = tr + g * 8;      // 8 consecutive k, kb%8==0
            idx = (size_t)f * NH + ((((kb >> 3) ^ (f & 7))) << 3);
        } else {
            int h  = tc + j;          // output row within chunk
            int fb = tr + g * 8;      // 8 consecutive f, same 32-chunk
            idx = ((size_t)(fb >> 5) * NH + h) * 32 + (fb & 31);
        }
        *(bf16x8*)(dst + idx) = v;
    }
}

// ---------------------------------------------------------------------------
// Kernel 2: fused expert FFN, v8 = v7 + work-stealing + single-barrier chunks.
//  - WORK-STEALING: 8 atomic counters (one per XCD expert-pair). 96 blocks
//    per xcd-group pop tiles of their 2 experts until the pool is empty ->
//    wall ~1.35 tile-times instead of 2.0 (fixes the 16-of-48-blocks-do-2-
//    tiles tail that held occupancy at 23%). L2 locality preserved.
//  - SINGLE BARRIER PER CHUNK: GEMM2 pipelined one chunk behind GEMM1.
//    iter ch: {DMA(ch+1) || bf2(ch) || GEMM1(ch)->Hs[ch%3]} ->
//             vmcnt(4)+lgkmcnt(0)+s_barrier -> GEMM2(ch-1).
//    Hs triple-buffered (read(j)@iter j+1 vs rewrite@iter j+3 separated by
//    barrier(j+2)). vmcnt FIFO at barrier(ch): [bf2n(ch-1)x4, DMA(ch+1)x4,
//    bf2n(ch)x4] -> vmcnt(4) retires exactly DMA(ch+1)+bf2n(ch-1).
//    17 barriers/tile vs 32.
//  - LDS ~51.7 KB -> 3 blocks/CU.
// ---------------------------------------------------------------------------
__global__ __launch_bounds__(256, 3) void moe_kernel(
    const bf16_t* __restrict__ xb,
    const bf16_t* __restrict__ w1t,  // [E][F][H] bf16, k-swizzled
    const float*  __restrict__ b1,
    const bf16_t* __restrict__ w2t,  // [E][F/32][H][32] bf16 chunked
    const float*  __restrict__ b2,
    const int* __restrict__ counts,
    const int* __restrict__ bucket_enc,
    const float* __restrict__ bucket_gw,
    bf16_t* __restrict__ pairbuf,    // [NTOK*2][NH] bf16
    int* __restrict__ work_ctr)      // [8] zeroed
{
    __shared__ uint4 W1s4[2][1024];                        // 32 KB (2x16KB)
    __shared__ __align__(16) bf16_t Hs[3][TT][HS_STRIDE];  // 15360 B
    __shared__ int   tok_s[TT];
    __shared__ float gw_s[TT];
    __shared__ float b1_s[NF];                             // 2 KB
    __shared__ float b2_s[NH];                             // 1 KB
    __shared__ int   witem_s;
    // ~51.7 KB -> 3 blocks/CU (12 waves/CU)

    int xcd  = blockIdx.x & 7;           // 96 blocks per xcd-group (768 grid)
    int e0   = xcd * 2;                  // this group's expert pair
    int wave = threadIdx.x >> 6;
    int lane = threadIdx.x & 63;
    int l15 = lane & 15, q = lane >> 4;

    int n0 = counts[e0], n1 = counts[e0 + 1];
    int nt0 = (n0 + TT - 1) / TT;
    int Tpair = nt0 + (n1 + TT - 1) / TT;

    while (true) {
        if (threadIdx.x == 0) witem_s = atomicAdd(&work_ctr[xcd], 1);
        __syncthreads();                 // witem visible; prev item fully done
        int w = witem_s;
        if (w >= Tpair) break;
        int e, tile, n_e;
        if (w < nt0) { e = e0;     tile = w;       n_e = n0; }
        else         { e = e0 + 1; tile = w - nt0; n_e = n1; }

        const bf16_t* w1te = w1t + (size_t)e * NF * NH;
        const bf16_t* w2te = w2t + (size_t)e * NF * NH;
        int tstart = tile * TT;

        if (threadIdx.x < TT) {
            int slot = tstart + threadIdx.x;
            if (slot < n_e) {
                tok_s[threadIdx.x] = bucket_enc[e * NTOK + slot];
                gw_s [threadIdx.x] = bucket_gw [e * NTOK + slot];
            } else { tok_s[threadIdx.x] = 0; gw_s[threadIdx.x] = 0.f; }
        }
        // per-item biases -> LDS (drained by the full-drain sync below)
        b1_s[threadIdx.x]       = b1[e * NF + threadIdx.x];
        b1_s[threadIdx.x + 256] = b1[e * NF + threadIdx.x + 256];
        b2_s[threadIdx.x]       = b2[e * NH + threadIdx.x];
        __syncthreads();                 // tok_s ready for the gather below

        // issue w1 chunks 0 and 1 -> W1s[0], W1s[1] (async DMA)
        {
            const uint4* gw1 = (const uint4*)w1te;
            #pragma unroll
            for (int i = 0; i < 4; i++)
                load_lds16(gw1 + i * 256 + threadIdx.x, &W1s4[0][i * 256 + threadIdx.x]);
            gw1 += 1024;
            #pragma unroll
            for (int i = 0; i < 4; i++)
                load_lds16(gw1 + i * 256 + threadIdx.x, &W1s4[1][i * 256 + threadIdx.x]);
        }
        // this wave's 16 X rows into registers (B-frags for GEMM1)
        int mytok = tok_s[wave * 16 + l15] & 0xFFFFF;
        const uint4* xrow = (const uint4*)(xb + (size_t)mytok * NH);
        uint4 xf[8];
        #pragma unroll
        for (int ks = 0; ks < 8; ks++) xf[ks] = xrow[ks * 4 + q];
        // w2 A-frags for chunk 0 (register double-buffer)
        bf16x8 bf2c[4], bf2n[4];
        #pragma unroll
        for (int nt = 0; nt < 4; nt++) {
            int hh = wave * 64 + nt * 16 + l15;
            bf2c[nt] = *(const bf16x8*)&w2te[((size_t)hh << 5) + q * 8];
        }
        __syncthreads();   // full drain: W1s[0..1], xf, bf2c, b1_s/b2_s ready

        f32x4 oacc[4][4];
        #pragma unroll
        for (int a = 0; a < 4; a++)
            #pragma unroll
            for (int b = 0; b < 4; b++) { f32x4 z = {0.f,0.f,0.f,0.f}; oacc[a][b] = z; }

        // GEMM1 for chunk ch from W1s[wbuf] -> Hs[hw]
        auto gemm1 = [&](int ch, int wbuf, int hw) {
            f32x4 hacc[2]; { f32x4 z = {0.f,0.f,0.f,0.f}; hacc[0] = z; hacc[1] = z; }
            const bf16_t* w1s = (const bf16_t*)W1s4[wbuf];
            #pragma unroll
            for (int ks = 0; ks < 8; ks++) {
                bf16x8 xfrag = *(const bf16x8*)&xf[ks];
                #pragma unroll
                for (int n = 0; n < 2; n++) {
                    int fl = n * 16 + l15;
                    bf16x8 wf = *(const bf16x8*)&w1s[fl * NH + ((((ks * 4 + q) ^ (fl & 7))) << 3)];
                    hacc[n] = __builtin_amdgcn_mfma_f32_16x16x32_bf16(wf, xfrag, hacc[n], 0, 0, 0);
                }
            }
            #pragma unroll
            for (int n = 0; n < 2; n++) {
                int f0 = ch * 32 + n * 16 + q * 4;
                float4 b1v = *(const float4*)&b1_s[f0];
                bf16x4 hv;
                #pragma unroll
                for (int r = 0; r < 4; r++) {
                    float v = hacc[n][r] + ((const float*)&b1v)[r];
                    v = v > 0.f ? v : 0.f;
                    hv[r] = (bf16_t)v;
                }
                *(bf16x4*)&Hs[hw][wave * 16 + l15][n * 16 + q * 4] = hv;
            }
        };
        // GEMM2 for chunk ch-1 from Hs[hr] with bf2c
        auto gemm2 = [&](int hr) {
            #pragma unroll
            for (int mt = 0; mt < 4; mt++) {
                bf16x8 hf = *(const bf16x8*)&Hs[hr][mt * 16 + l15][q * 8];
                #pragma unroll
                for (int nt = 0; nt < 4; nt++) {
                    oacc[mt][nt] = __builtin_amdgcn_mfma_f32_16x16x32_bf16(bf2c[nt], hf, oacc[mt][nt], 0, 0, 0);
                }
            }
        };

        // prologue: GEMM1(0) -> Hs[0]; barrier (no vmem outstanding here)
        gemm1(0, 0, 0);
        asm volatile("s_waitcnt lgkmcnt(0)" ::: "memory");
        __builtin_amdgcn_s_barrier();
        __builtin_amdgcn_sched_barrier(0);

        int hw = 1, hr = 0;
        for (int ch = 1; ch < NCH; ch++) {
            // -- async prefetch w1 chunk ch+1 -> W1s[(ch+1)&1]
            if (ch + 1 < NCH) {
                const uint4* gw1 = (const uint4*)w1te + (size_t)(ch + 1) * 1024;
                #pragma unroll
                for (int i = 0; i < 4; i++)
                    load_lds16(gw1 + i * 256 + threadIdx.x,
                               &W1s4[(ch + 1) & 1][i * 256 + threadIdx.x]);
            }
            // -- w2 A-frags for chunk ch (used by GEMM2(ch) next iteration)
            #pragma unroll
            for (int nt = 0; nt < 4; nt++) {
                int hh = wave * 64 + nt * 16 + l15;
                bf2n[nt] = *(const bf16x8*)&w2te[(((size_t)ch * NH + hh) << 5) + q * 8];
            }
            // ---- GEMM1(ch): needs W1s[ch&1], DMA'd last iter, waited at prev barrier
            gemm1(ch, ch & 1, hw);
            // ---- the ONE barrier: DMA(ch+1) done (vmcnt 4), Hs[hw] visible
            asm volatile("s_waitcnt vmcnt(4) lgkmcnt(0)" ::: "memory");
            __builtin_amdgcn_s_barrier();
            __builtin_amdgcn_sched_barrier(0);
            // ---- GEMM2(ch-1) from Hs[hr]
            gemm2(hr);
            #pragma unroll
            for (int nt = 0; nt < 4; nt++) bf2c[nt] = bf2n[nt];
            hw = (hw == 2) ? 0 : hw + 1;
            hr = (hr == 2) ? 0 : hr + 1;
        }
        // post-loop: GEMM2(15) from Hs[(NCH-1)%3] (= Hs[0])
        gemm2((NCH - 1) % 3);

        // ---- epilogue: lane holds 4 consecutive h-cols per (mt,nt) for ONE
        //      token -> +b2(LDS), *gate_w, single 8B store.
        int nrows = n_e - tstart; if (nrows > TT) nrows = TT;
        float4 b2v[4];
        #pragma unroll
        for (int nt = 0; nt < 4; nt++)
            b2v[nt] = *(const float4*)&b2_s[wave * 64 + nt * 16 + q * 4];
        #pragma unroll
        for (int mt = 0; mt < 4; mt++) {
            int trow = mt * 16 + l15;
            int enc  = tok_s[trow];
            float gw = gw_s[trow];
            bool valid = trow < nrows;
            int tok = enc & 0xFFFFF;
            int kk  = enc >> 20;
            bf16_t* orow = pairbuf + ((size_t)(tok * 2 + kk)) * NH;
            #pragma unroll
            for (int nt = 0; nt < 4; nt++) {
                int col = wave * 64 + nt * 16 + q * 4;
                bf16x4 ov;
                #pragma unroll
                for (int r = 0; r < 4; r++)
                    ov[r] = (bf16_t)((oacc[mt][nt][r] + ((const float*)&b2v[nt])[r]) * gw);
                if (valid) *(bf16x4*)&orow[col] = ov;
            }
        }
    }
}

// ---------------------------------------------------------------------------
// Kernel 3: residual + LayerNorm, vectorized. Wave-per-token (64 lanes x 4 h),
// float4/bf16x4 loads, shfl_xor reduce, no LDS, no syncthreads.
// ---------------------------------------------------------------------------
__global__ __launch_bounds__(256) void ln_kernel(
    const float* __restrict__ x, const bf16_t* __restrict__ pairbuf,
    const float* __restrict__ gamma, const float* __restrict__ beta,
    float* __restrict__ out)
{
    int tok  = blockIdx.x * 4 + (threadIdx.x >> 6);
    int lane = threadIdx.x & 63;
    float4 xv = *(const float4*)(x + (size_t)tok * NH + lane * 4);
    bf16x4 p0 = *(const bf16x4*)(pairbuf + (size_t)(tok * 2)     * NH + lane * 4);
    bf16x4 p1 = *(const bf16x4*)(pairbuf + (size_t)(tok * 2 + 1) * NH + lane * 4);
    float y0 = xv.x + (float)p0[0] + (float)p1[0];
    float y1 = xv.y + (float)p0[1] + (float)p1[1];
    float y2 = xv.z + (float)p0[2] + (float)p1[2];
    float y3 = xv.w + (float)p0[3] + (float)p1[3];
    float s  = y0 + y1 + y2 + y3;
    float s2 = y0 * y0 + y1 * y1 + y2 * y2 + y3 * y3;
    #pragma unroll
    for (int o = 32; o > 0; o >>= 1) {
        s  += __shfl_xor(s, o);
        s2 += __shfl_xor(s2, o);
    }
    float mu   = s * (1.f / NH);
    float var  = s2 * (1.f / NH) - mu * mu;
    float rstd = rsqrtf(var + 1e-5f);
    float4 gv = *(const float4*)(gamma + lane * 4);
    float4 bv = *(const float4*)(beta  + lane * 4);
    float4 o4;
    o4.x = (y0 - mu) * rstd * gv.x + bv.x;
    o4.y = (y1 - mu) * rstd * gv.y + bv.y;
    o4.z = (y2 - mu) * rstd * gv.z + bv.z;
    o4.w = (y3 - mu) * rstd * gv.w + bv.w;
    *(float4*)(out + (size_t)tok * NH + lane * 4) = o4;
}

// ---------------------------------------------------------------------------
extern "C" void kernel_launch(void* const* d_in, const int* in_sizes, int n_in,
                              void* d_out, int out_size, void* d_ws, size_t ws_size,
                              hipStream_t stream) {
    const float* x      = (const float*)d_in[0];
    const float* gate_w = (const float*)d_in[1];
    const float* gate_b = (const float*)d_in[2];
    const float* w1     = (const float*)d_in[3];
    const float* b1     = (const float*)d_in[4];
    const float* w2     = (const float*)d_in[5];
    const float* b2     = (const float*)d_in[6];
    const float* gamma  = (const float*)d_in[7];
    const float* beta   = (const float*)d_in[8];
    float* out = (float*)d_out;

    char* ws = (char*)d_ws;
    const size_t MB = 1024 * 1024;
    int*    counts     = (int*)ws;                       // 64 B used
    int*    work_ctr   = (int*)(ws + 128);               // 32 B used (in memset range)
    int*    bucket_enc = (int*)(ws + 256);               // 2 MB
    float*  bucket_gw  = (float*)(ws + 256 + 2 * MB);    // 2 MB
    bf16_t* w1t        = (bf16_t*)(ws + 256 + 4 * MB);   // 4 MB
    bf16_t* w2t        = (bf16_t*)(ws + 256 + 8 * MB);   // 4 MB
    bf16_t* xb         = (bf16_t*)(ws + 256 + 12 * MB);  // 16 MB
    bf16_t* pairbuf    = (bf16_t*)(ws + 256 + 28 * MB);  // 32 MB

    hipMemsetAsync(counts, 0, 256, stream);
    prep_kernel<<<4224, 256, 0, stream>>>(w1, w2, w1t, w2t,
                                          x, gate_w, gate_b,
                                          counts, bucket_enc, bucket_gw, xb);
    moe_kernel<<<768, 256, 0, stream>>>(xb, w1t, b1, w2t, b2, counts,
                                        bucket_enc, bucket_gw, pairbuf, work_ctr);
    ln_kernel<<<NTOK / 4, 256, 0, stream>>>(x, pairbuf, gamma, beta, out);
}